// Round 2
// baseline (316.324 us; speedup 1.0000x reference)
//
#include <hip/hip_runtime.h>
#include <math.h>

#define NTOK 8192   // B*S = 4*2048
#define HDIM 2048
#define FDIM 8192
#define NEXP 8

// ---------------- router: logits = x@Wr + br, softmax, top-2; also zeroes tok ----------
// 512 blocks x 256 thr; wave handles 4 tokens, lanes split H; butterfly reduce.
__global__ __launch_bounds__(256) void router_kernel(const float* __restrict__ x,
                                                     const float* __restrict__ Wr,
                                                     const float* __restrict__ br,
                                                     float* __restrict__ G,
                                                     int* __restrict__ sel,
                                                     float* __restrict__ tok) {
  // zero tok[16][2048] (needed by tok_kernel's atomics); 8192 float4 writes
  {
    const int idx = blockIdx.x * 256 + threadIdx.x;
    if (idx < (16 * HDIM) / 4) *(float4*)(tok + idx * 4) = make_float4(0.f, 0.f, 0.f, 0.f);
  }
  const int wave = threadIdx.x >> 6;
  const int lane = threadIdx.x & 63;
  const int n0 = (blockIdx.x * 4 + wave) * 4;

  float acc[4][8];
#pragma unroll
  for (int t = 0; t < 4; ++t)
#pragma unroll
    for (int e = 0; e < 8; ++e) acc[t][e] = 0.f;

  for (int j = 0; j < 32; ++j) {
    const int h = lane + (j << 6);
    float4 wa = *(const float4*)(Wr + h * 8);
    float4 wb = *(const float4*)(Wr + h * 8 + 4);
    float w[8] = {wa.x, wa.y, wa.z, wa.w, wb.x, wb.y, wb.z, wb.w};
#pragma unroll
    for (int t = 0; t < 4; ++t) {
      float xv = x[(size_t)(n0 + t) * HDIM + h];
#pragma unroll
      for (int e = 0; e < 8; ++e) acc[t][e] = fmaf(xv, w[e], acc[t][e]);
    }
  }

#pragma unroll
  for (int t = 0; t < 4; ++t)
#pragma unroll
    for (int e = 0; e < 8; ++e) {
      float v = acc[t][e];
      v += __shfl_xor(v, 1, 64);
      v += __shfl_xor(v, 2, 64);
      v += __shfl_xor(v, 4, 64);
      v += __shfl_xor(v, 8, 64);
      v += __shfl_xor(v, 16, 64);
      v += __shfl_xor(v, 32, 64);
      acc[t][e] = v;
    }

  if (lane == 0) {
    float brv[8];
#pragma unroll
    for (int e = 0; e < 8; ++e) brv[e] = br[e];
#pragma unroll
    for (int t = 0; t < 4; ++t) {
      float l[8];
#pragma unroll
      for (int e = 0; e < 8; ++e) l[e] = acc[t][e] + brv[e];
      float m = l[0];
#pragma unroll
      for (int e = 1; e < 8; ++e) m = fmaxf(m, l[e]);
      float s = 0.f;
#pragma unroll
      for (int e = 0; e < 8; ++e) s += expf(l[e] - m);
      float best = l[0], second = -3.4e38f;
      int bi = 0, si = 0;
#pragma unroll
      for (int e = 1; e < 8; ++e) {
        float v = l[e];
        if (v > best) { second = best; si = bi; best = v; bi = e; }
        else if (v > second) { second = v; si = e; }
      }
      const int n = n0 + t;
      const float inv = 1.f / s;
      G[n * 2 + 0] = expf(best - m) * inv;
      G[n * 2 + 1] = expf(second - m) * inv;
      sel[n * 2 + 0] = bi;
      sel[n * 2 + 1] = si;
    }
  }
}

// ---------------- tok[e,k,h] = sum over tokens routed to (e,k) of x[n,h] ----------------
__global__ __launch_bounds__(256) void tok_kernel(const float* __restrict__ x,
                                                  const int* __restrict__ sel,
                                                  float* __restrict__ tok) {
  __shared__ float part[16][256];
  __shared__ int sidx[256];
  const int tid = threadIdx.x;
  const int h0 = blockIdx.x << 8;
  const int n0 = blockIdx.y << 7;  // 128 tokens per block
#pragma unroll
  for (int s = 0; s < 16; ++s) part[s][tid] = 0.f;
  sidx[tid] = sel[(n0 << 1) + tid];
  __syncthreads();
  for (int i = 0; i < 128; ++i) {
    float v = x[(size_t)(n0 + i) * HDIM + h0 + tid];
    int s0 = sidx[2 * i] << 1;            // (e0, k=0)
    int s1 = (sidx[2 * i + 1] << 1) + 1;  // (e1, k=1)
    part[s0][tid] += v;
    part[s1][tid] += v;
  }
#pragma unroll
  for (int s = 0; s < 16; ++s) atomicAdd(&tok[s * HDIM + h0 + tid], part[s][tid]);
}

// ---------------- up-proj partials: up_part[e][hc][k][f] = sum_{h in chunk} tok*W1 -------
// grid (8 fx, 16 hc, 8 e); thread = 1 float4 of f; 128 h per block; write-once, no atomics.
__global__ __launch_bounds__(256) void up_kernel(const float* __restrict__ tok,
                                                 const float* __restrict__ W1,
                                                 float* __restrict__ up_part) {
  const int e = blockIdx.z;
  const int hc = blockIdx.y;
  const int tid = threadIdx.x;
  const int f = (blockIdx.x << 10) + (tid << 2);
  const int h0 = hc << 7;
  __shared__ float t0s[128], t1s[128];
  if (tid < 128) t0s[tid] = tok[(e * 2 + 0) * HDIM + h0 + tid];
  else           t1s[tid - 128] = tok[(e * 2 + 1) * HDIM + h0 + (tid - 128)];
  __syncthreads();
  const float* Wp = W1 + ((size_t)e * HDIM + h0) * FDIM + f;
  float4 a0 = make_float4(0.f, 0.f, 0.f, 0.f), a1 = make_float4(0.f, 0.f, 0.f, 0.f);
#pragma unroll 8
  for (int hh = 0; hh < 128; ++hh) {
    float4 w = *(const float4*)(Wp + (size_t)hh * FDIM);
    float t0 = t0s[hh], t1 = t1s[hh];
    a0.x = fmaf(t0, w.x, a0.x); a0.y = fmaf(t0, w.y, a0.y);
    a0.z = fmaf(t0, w.z, a0.z); a0.w = fmaf(t0, w.w, a0.w);
    a1.x = fmaf(t1, w.x, a1.x); a1.y = fmaf(t1, w.y, a1.y);
    a1.z = fmaf(t1, w.z, a1.z); a1.w = fmaf(t1, w.w, a1.w);
  }
  float* p0 = up_part + ((size_t)((e * 16 + hc) * 2 + 0) * FDIM) + f;
  float* p1 = up_part + ((size_t)((e * 16 + hc) * 2 + 1) * FDIM) + f;
  *(float4*)p0 = a0;
  *(float4*)p1 = a1;
}

// ---------------- reduce over hc + bias + exact GELU: mid[e][k][f] ----------------
__global__ __launch_bounds__(256) void gelu_reduce_kernel(const float* __restrict__ up_part,
                                                          const float* __restrict__ b1,
                                                          float* __restrict__ mid) {
  const int i4 = blockIdx.x * 256 + threadIdx.x;  // 32768 threads: 16*8192/4
  const int f = (i4 & (FDIM / 4 - 1)) << 2;
  const int ek = i4 >> 11;                        // 0..15
  const int e = ek >> 1;
  float4 s = make_float4(0.f, 0.f, 0.f, 0.f);
#pragma unroll
  for (int hc = 0; hc < 16; ++hc) {
    float4 v = *(const float4*)(up_part + ((size_t)((e * 16 + hc) * 2 + (ek & 1)) * FDIM) + f);
    s.x += v.x; s.y += v.y; s.z += v.z; s.w += v.w;
  }
  float4 b = *(const float4*)(b1 + e * FDIM + f);
  s.x += b.x; s.y += b.y; s.z += b.z; s.w += b.w;
  float4 r;
  r.x = 0.5f * s.x * (1.f + erff(s.x * 0.70710678118654752f));
  r.y = 0.5f * s.y * (1.f + erff(s.y * 0.70710678118654752f));
  r.z = 0.5f * s.z * (1.f + erff(s.z * 0.70710678118654752f));
  r.w = 0.5f * s.w * (1.f + erff(s.w * 0.70710678118654752f));
  *(float4*)(mid + (size_t)ek * FDIM + f) = r;
}

// ---------------- down-proj partials: down_part[e][fc][k][h] -----------------------------
// grid (64 fc, 2 hc, 8 e); thread = 1 float4 of h; 128 f per block; write-once, no atomics.
__global__ __launch_bounds__(256) void down_kernel(const float* __restrict__ mid,
                                                   const float* __restrict__ W2,
                                                   float* __restrict__ down_part) {
  const int e = blockIdx.z;
  const int fc = blockIdx.x;
  const int tid = threadIdx.x;
  const int f0 = fc << 7;
  const int h = (blockIdx.y << 10) + (tid << 2);
  __shared__ float m0s[128], m1s[128];
  if (tid < 128) m0s[tid] = mid[(e * 2 + 0) * FDIM + f0 + tid];
  else           m1s[tid - 128] = mid[(e * 2 + 1) * FDIM + f0 + (tid - 128)];
  __syncthreads();
  const float* Wp = W2 + ((size_t)e * FDIM + f0) * HDIM + h;
  float4 a0 = make_float4(0.f, 0.f, 0.f, 0.f), a1 = make_float4(0.f, 0.f, 0.f, 0.f);
#pragma unroll 8
  for (int ff = 0; ff < 128; ++ff) {
    float4 w = *(const float4*)(Wp + (size_t)ff * HDIM);
    float m0 = m0s[ff], m1 = m1s[ff];
    a0.x = fmaf(m0, w.x, a0.x); a0.y = fmaf(m0, w.y, a0.y);
    a0.z = fmaf(m0, w.z, a0.z); a0.w = fmaf(m0, w.w, a0.w);
    a1.x = fmaf(m1, w.x, a1.x); a1.y = fmaf(m1, w.y, a1.y);
    a1.z = fmaf(m1, w.z, a1.z); a1.w = fmaf(m1, w.w, a1.w);
  }
  float* p0 = down_part + ((size_t)((e * 64 + fc) * 2 + 0) * HDIM) + h;
  float* p1 = down_part + ((size_t)((e * 64 + fc) * 2 + 1) * HDIM) + h;
  *(float4*)p0 = a0;
  *(float4*)p1 = a1;
}

// ---------------- ebar[k][h] = sum over 512 partials + sum_e b2[e][h] ----------------
__global__ __launch_bounds__(256) void ebar_reduce_kernel(const float* __restrict__ down_part,
                                                          const float* __restrict__ b2,
                                                          float* __restrict__ ebar) {
  const int i4 = blockIdx.x * 256 + threadIdx.x;  // 1024 threads: 2*2048/4
  const int k = i4 >> 9;
  const int h = (i4 & 511) << 2;
  float4 s = make_float4(0.f, 0.f, 0.f, 0.f);
#pragma unroll
  for (int e = 0; e < 8; ++e) {
    float4 b = *(const float4*)(b2 + e * HDIM + h);
    s.x += b.x; s.y += b.y; s.z += b.z; s.w += b.w;
  }
#pragma unroll 8
  for (int p = 0; p < 512; ++p) {
    float4 v = *(const float4*)(down_part + ((size_t)(p * 2 + k) * HDIM) + h);
    s.x += v.x; s.y += v.y; s.z += v.z; s.w += v.w;
  }
  *(float4*)(ebar + k * HDIM + h) = s;
}

// ---------------- combine: y[n,h] = G[n,0]*ebar[0,h] + G[n,1]*ebar[1,h] ----------------
__global__ __launch_bounds__(256) void combine_kernel(const float* __restrict__ G,
                                                      const float* __restrict__ ebar,
                                                      float* __restrict__ y) {
  const int i4 = blockIdx.x * 256 + threadIdx.x;  // NTOK*HDIM/4 = 4194304 total
  const int n = i4 >> 9;
  const int h = (i4 & 511) << 2;
  const float g0 = G[n * 2 + 0], g1 = G[n * 2 + 1];
  float4 e0 = *(const float4*)(ebar + h);
  float4 e1 = *(const float4*)(ebar + HDIM + h);
  float4 r;
  r.x = fmaf(g0, e0.x, g1 * e1.x);
  r.y = fmaf(g0, e0.y, g1 * e1.y);
  r.z = fmaf(g0, e0.z, g1 * e1.z);
  r.w = fmaf(g0, e0.w, g1 * e1.w);
  *(float4*)(y + ((size_t)n << 11) + h) = r;
}

extern "C" void kernel_launch(void* const* d_in, const int* in_sizes, int n_in,
                              void* d_out, int out_size, void* d_ws, size_t ws_size,
                              hipStream_t stream) {
  const float* x  = (const float*)d_in[0];
  const float* Wr = (const float*)d_in[1];
  const float* br = (const float*)d_in[2];
  const float* W1 = (const float*)d_in[3];
  const float* b1 = (const float*)d_in[4];
  const float* W2 = (const float*)d_in[5];
  const float* b2 = (const float*)d_in[6];
  float* y = (float*)d_out;

  char* ws = (char*)d_ws;
  float* G         = (float*)(ws);              // 64 KB
  int*   sel       = (int*)(ws + (64 << 10));   // 64 KB
  float* tok       = (float*)(ws + (128 << 10));// 128 KB
  float* mid       = (float*)(ws + (256 << 10));// 512 KB
  float* up_part   = (float*)(ws + (768 << 10));            // 8 MB: [8][16][2][8192]
  float* down_part = (float*)(ws + (768 << 10) + (8 << 20));// 8 MB: [8][64][2][2048]
  float* ebar      = (float*)(ws + (768 << 10) + (16 << 20));// 16 KB

  router_kernel<<<512, 256, 0, stream>>>(x, Wr, br, G, sel, tok);
  tok_kernel<<<dim3(8, 64), 256, 0, stream>>>(x, sel, tok);
  up_kernel<<<dim3(8, 16, 8), 256, 0, stream>>>(tok, W1, up_part);
  gelu_reduce_kernel<<<128, 256, 0, stream>>>(up_part, b1, mid);
  down_kernel<<<dim3(64, 2, 8), 256, 0, stream>>>(mid, W2, down_part);
  ebar_reduce_kernel<<<4, 256, 0, stream>>>(down_part, b2, ebar);
  combine_kernel<<<16384, 256, 0, stream>>>(G, ebar, y);
}

// Round 4
// 259.376 us; speedup vs baseline: 1.2196x; 1.2196x over previous
//
#include <hip/hip_runtime.h>
#include <math.h>

#define NTOK 8192   // B*S = 4*2048
#define HDIM 2048
#define FDIM 8192
#define NEXP 8

typedef float f32x4 __attribute__((ext_vector_type(4)));

// ---------------- router: logits = x@Wr + br, softmax, top-2; also zeroes tok ----------
__global__ __launch_bounds__(256) void router_kernel(const float* __restrict__ x,
                                                     const float* __restrict__ Wr,
                                                     const float* __restrict__ br,
                                                     float* __restrict__ G,
                                                     int* __restrict__ sel,
                                                     float* __restrict__ tok) {
  {
    const int idx = blockIdx.x * 256 + threadIdx.x;
    if (idx < (16 * HDIM) / 4) *(float4*)(tok + idx * 4) = make_float4(0.f, 0.f, 0.f, 0.f);
  }
  const int wave = threadIdx.x >> 6;
  const int lane = threadIdx.x & 63;
  const int n0 = (blockIdx.x * 4 + wave) * 4;

  float acc[4][8];
#pragma unroll
  for (int t = 0; t < 4; ++t)
#pragma unroll
    for (int e = 0; e < 8; ++e) acc[t][e] = 0.f;

#pragma unroll 4
  for (int j = 0; j < 32; ++j) {
    const int h = lane + (j << 6);
    float4 wa = *(const float4*)(Wr + h * 8);
    float4 wb = *(const float4*)(Wr + h * 8 + 4);
    float w[8] = {wa.x, wa.y, wa.z, wa.w, wb.x, wb.y, wb.z, wb.w};
#pragma unroll
    for (int t = 0; t < 4; ++t) {
      float xv = x[(size_t)(n0 + t) * HDIM + h];
#pragma unroll
      for (int e = 0; e < 8; ++e) acc[t][e] = fmaf(xv, w[e], acc[t][e]);
    }
  }

#pragma unroll
  for (int t = 0; t < 4; ++t)
#pragma unroll
    for (int e = 0; e < 8; ++e) {
      float v = acc[t][e];
      v += __shfl_xor(v, 1, 64);
      v += __shfl_xor(v, 2, 64);
      v += __shfl_xor(v, 4, 64);
      v += __shfl_xor(v, 8, 64);
      v += __shfl_xor(v, 16, 64);
      v += __shfl_xor(v, 32, 64);
      acc[t][e] = v;
    }

  if (lane == 0) {
    float brv[8];
#pragma unroll
    for (int e = 0; e < 8; ++e) brv[e] = br[e];
#pragma unroll
    for (int t = 0; t < 4; ++t) {
      float l[8];
#pragma unroll
      for (int e = 0; e < 8; ++e) l[e] = acc[t][e] + brv[e];
      float m = l[0];
#pragma unroll
      for (int e = 1; e < 8; ++e) m = fmaxf(m, l[e]);
      float s = 0.f;
#pragma unroll
      for (int e = 0; e < 8; ++e) s += expf(l[e] - m);
      float best = l[0], second = -3.4e38f;
      int bi = 0, si = 0;
#pragma unroll
      for (int e = 1; e < 8; ++e) {
        float v = l[e];
        if (v > best) { second = best; si = bi; best = v; bi = e; }
        else if (v > second) { second = v; si = e; }
      }
      const int n = n0 + t;
      const float inv = 1.f / s;
      G[n * 2 + 0] = expf(best - m) * inv;
      G[n * 2 + 1] = expf(second - m) * inv;
      sel[n * 2 + 0] = bi;
      sel[n * 2 + 1] = si;
    }
  }
}

// ---------------- tok[e,k,h] = sum over tokens routed to (e,k) of x[n,h] ----------------
__global__ __launch_bounds__(256) void tok_kernel(const float* __restrict__ x,
                                                  const int* __restrict__ sel,
                                                  float* __restrict__ tok) {
  __shared__ float part[16][256];
  __shared__ int sidx[256];
  const int tid = threadIdx.x;
  const int h0 = blockIdx.x << 8;
  const int n0 = blockIdx.y << 7;  // 128 tokens per block
#pragma unroll
  for (int s = 0; s < 16; ++s) part[s][tid] = 0.f;
  sidx[tid] = sel[(n0 << 1) + tid];
  __syncthreads();
#pragma unroll 4
  for (int i = 0; i < 128; ++i) {
    float v = x[(size_t)(n0 + i) * HDIM + h0 + tid];
    int s0 = sidx[2 * i] << 1;            // (e0, k=0)
    int s1 = (sidx[2 * i + 1] << 1) + 1;  // (e1, k=1)
    part[s0][tid] += v;
    part[s1][tid] += v;
  }
#pragma unroll
  for (int s = 0; s < 16; ++s) atomicAdd(&tok[s * HDIM + h0 + tid], part[s][tid]);
}

// ---------------- up-proj partials: up_part[e][hc][k][f], 128 h per block ----------------
__global__ __launch_bounds__(256) void up_kernel(const float* __restrict__ tok,
                                                 const float* __restrict__ W1,
                                                 float* __restrict__ up_part) {
  const int e = blockIdx.z;
  const int hc = blockIdx.y;
  const int tid = threadIdx.x;
  const int f = (blockIdx.x << 10) + (tid << 2);
  const int h0 = hc << 7;
  __shared__ float t0s[128], t1s[128];
  if (tid < 128) t0s[tid] = tok[(e * 2 + 0) * HDIM + h0 + tid];
  else           t1s[tid - 128] = tok[(e * 2 + 1) * HDIM + h0 + (tid - 128)];
  __syncthreads();
  const float* Wp = W1 + ((size_t)e * HDIM + h0) * FDIM + f;
  float4 a0 = make_float4(0.f, 0.f, 0.f, 0.f), a1 = make_float4(0.f, 0.f, 0.f, 0.f);
#pragma unroll 16
  for (int hh = 0; hh < 128; ++hh) {
    f32x4 w = __builtin_nontemporal_load(reinterpret_cast<const f32x4*>(Wp + (size_t)hh * FDIM));
    float t0 = t0s[hh], t1 = t1s[hh];
    a0.x = fmaf(t0, w.x, a0.x); a0.y = fmaf(t0, w.y, a0.y);
    a0.z = fmaf(t0, w.z, a0.z); a0.w = fmaf(t0, w.w, a0.w);
    a1.x = fmaf(t1, w.x, a1.x); a1.y = fmaf(t1, w.y, a1.y);
    a1.z = fmaf(t1, w.z, a1.z); a1.w = fmaf(t1, w.w, a1.w);
  }
  float* p0 = up_part + ((size_t)((e * 16 + hc) * 2 + 0) * FDIM) + f;
  float* p1 = up_part + ((size_t)((e * 16 + hc) * 2 + 1) * FDIM) + f;
  *(float4*)p0 = a0;
  *(float4*)p1 = a1;
}

// ------- reduce over hc + bias + exact GELU -> mid; also seeds ebar with sum_e b2 -------
__global__ __launch_bounds__(256) void gelu_reduce_kernel(const float* __restrict__ up_part,
                                                          const float* __restrict__ b1,
                                                          const float* __restrict__ b2,
                                                          float* __restrict__ mid,
                                                          float* __restrict__ ebar) {
  const int i4 = blockIdx.x * 256 + threadIdx.x;  // 32768 threads: 16*8192/4
  if (i4 < 1024) {  // seed ebar[2][2048]: k = i4>>9, h = (i4&511)*4
    const int h = (i4 & 511) << 2;
    float4 s = make_float4(0.f, 0.f, 0.f, 0.f);
#pragma unroll
    for (int e = 0; e < 8; ++e) {
      float4 b = *(const float4*)(b2 + e * HDIM + h);
      s.x += b.x; s.y += b.y; s.z += b.z; s.w += b.w;
    }
    *(float4*)(ebar + (i4 >> 9) * HDIM + h) = s;
  }
  const int f = (i4 & (FDIM / 4 - 1)) << 2;
  const int ek = i4 >> 11;                        // 0..15
  const int e = ek >> 1;
  float4 s = make_float4(0.f, 0.f, 0.f, 0.f);
#pragma unroll
  for (int hc = 0; hc < 16; ++hc) {
    float4 v = *(const float4*)(up_part + ((size_t)((e * 16 + hc) * 2 + (ek & 1)) * FDIM) + f);
    s.x += v.x; s.y += v.y; s.z += v.z; s.w += v.w;
  }
  float4 b = *(const float4*)(b1 + e * FDIM + f);
  s.x += b.x; s.y += b.y; s.z += b.z; s.w += b.w;
  float4 r;
  r.x = 0.5f * s.x * (1.f + erff(s.x * 0.70710678118654752f));
  r.y = 0.5f * s.y * (1.f + erff(s.y * 0.70710678118654752f));
  r.z = 0.5f * s.z * (1.f + erff(s.z * 0.70710678118654752f));
  r.w = 0.5f * s.w * (1.f + erff(s.w * 0.70710678118654752f));
  *(float4*)(mid + (size_t)ek * FDIM + f) = r;
}

// ---------------- down-proj partials: down_part[e][fc][k][h], fc=32, 256 f per block -----
__global__ __launch_bounds__(256) void down_kernel(const float* __restrict__ mid,
                                                   const float* __restrict__ W2,
                                                   float* __restrict__ down_part) {
  const int e = blockIdx.z;
  const int fc = blockIdx.x;           // 0..31
  const int tid = threadIdx.x;
  const int f0 = fc << 8;              // 256 f rows
  const int h = (blockIdx.y << 10) + (tid << 2);
  __shared__ float m0s[256], m1s[256];
  m0s[tid] = mid[(e * 2 + 0) * FDIM + f0 + tid];
  m1s[tid] = mid[(e * 2 + 1) * FDIM + f0 + tid];
  __syncthreads();
  const float* Wp = W2 + ((size_t)e * FDIM + f0) * HDIM + h;
  float4 a0 = make_float4(0.f, 0.f, 0.f, 0.f), a1 = make_float4(0.f, 0.f, 0.f, 0.f);
#pragma unroll 16
  for (int ff = 0; ff < 256; ++ff) {
    f32x4 w = __builtin_nontemporal_load(reinterpret_cast<const f32x4*>(Wp + (size_t)ff * HDIM));
    float m0 = m0s[ff], m1 = m1s[ff];
    a0.x = fmaf(m0, w.x, a0.x); a0.y = fmaf(m0, w.y, a0.y);
    a0.z = fmaf(m0, w.z, a0.z); a0.w = fmaf(m0, w.w, a0.w);
    a1.x = fmaf(m1, w.x, a1.x); a1.y = fmaf(m1, w.y, a1.y);
    a1.z = fmaf(m1, w.z, a1.z); a1.w = fmaf(m1, w.w, a1.w);
  }
  float* p0 = down_part + ((size_t)((e * 32 + fc) * 2 + 0) * HDIM) + h;
  float* p1 = down_part + ((size_t)((e * 32 + fc) * 2 + 1) * HDIM) + h;
  *(float4*)p0 = a0;
  *(float4*)p1 = a1;
}

// ---------------- ebar += coalesced reduction of down_part (256 slices) ----------------
// 64 blocks; block sums 4 (e,fc) combos over both k and all h; atomicAdd into seeded ebar.
__global__ __launch_bounds__(256) void ebar_reduce_kernel(const float* __restrict__ down_part,
                                                          float* __restrict__ ebar) {
  const int tid = threadIdx.x;
  const int c0 = blockIdx.x * 4;  // combos c = (e*32+fc) in [0,256)
  float4 acc[2][2];               // [k][h-round: h4 = tid, tid+256]
#pragma unroll
  for (int k = 0; k < 2; ++k)
#pragma unroll
    for (int r = 0; r < 2; ++r) acc[k][r] = make_float4(0.f, 0.f, 0.f, 0.f);
#pragma unroll
  for (int j = 0; j < 4; ++j) {
    const int c = c0 + j;
#pragma unroll
    for (int k = 0; k < 2; ++k) {
      const float* base = down_part + (size_t)(c * 2 + k) * HDIM;
#pragma unroll
      for (int r = 0; r < 2; ++r) {
        float4 v = *(const float4*)(base + ((r << 8) + tid) * 4);
        acc[k][r].x += v.x; acc[k][r].y += v.y; acc[k][r].z += v.z; acc[k][r].w += v.w;
      }
    }
  }
#pragma unroll
  for (int k = 0; k < 2; ++k)
#pragma unroll
    for (int r = 0; r < 2; ++r) {
      float* dst = ebar + k * HDIM + ((r << 8) + tid) * 4;
      atomicAdd(dst + 0, acc[k][r].x);
      atomicAdd(dst + 1, acc[k][r].y);
      atomicAdd(dst + 2, acc[k][r].z);
      atomicAdd(dst + 3, acc[k][r].w);
    }
}

// ---------------- combine: y[n,h] = G[n,0]*ebar[0,h] + G[n,1]*ebar[1,h] ----------------
__global__ __launch_bounds__(256) void combine_kernel(const float* __restrict__ G,
                                                      const float* __restrict__ ebar,
                                                      float* __restrict__ y) {
  const int i4 = blockIdx.x * 256 + threadIdx.x;  // NTOK*HDIM/4 = 4194304 total
  const int n = i4 >> 9;
  const int h = (i4 & 511) << 2;
  const float g0 = G[n * 2 + 0], g1 = G[n * 2 + 1];
  float4 e0 = *(const float4*)(ebar + h);
  float4 e1 = *(const float4*)(ebar + HDIM + h);
  f32x4 r;
  r.x = fmaf(g0, e0.x, g1 * e1.x);
  r.y = fmaf(g0, e0.y, g1 * e1.y);
  r.z = fmaf(g0, e0.z, g1 * e1.z);
  r.w = fmaf(g0, e0.w, g1 * e1.w);
  __builtin_nontemporal_store(r, reinterpret_cast<f32x4*>(y + ((size_t)n << 11) + h));
}

extern "C" void kernel_launch(void* const* d_in, const int* in_sizes, int n_in,
                              void* d_out, int out_size, void* d_ws, size_t ws_size,
                              hipStream_t stream) {
  const float* x  = (const float*)d_in[0];
  const float* Wr = (const float*)d_in[1];
  const float* br = (const float*)d_in[2];
  const float* W1 = (const float*)d_in[3];
  const float* b1 = (const float*)d_in[4];
  const float* W2 = (const float*)d_in[5];
  const float* b2 = (const float*)d_in[6];
  float* y = (float*)d_out;

  char* ws = (char*)d_ws;
  float* G         = (float*)(ws);               // 64 KB
  int*   sel       = (int*)(ws + (64 << 10));    // 64 KB
  float* tok       = (float*)(ws + (128 << 10)); // 128 KB
  float* mid       = (float*)(ws + (256 << 10)); // 512 KB
  float* up_part   = (float*)(ws + (768 << 10));             // 8 MB: [8][16][2][8192]
  float* down_part = (float*)(ws + (768 << 10) + (8 << 20)); // 4 MB: [8][32][2][2048]
  float* ebar      = (float*)(ws + (768 << 10) + (12 << 20));// 16 KB

  router_kernel<<<512, 256, 0, stream>>>(x, Wr, br, G, sel, tok);
  tok_kernel<<<dim3(8, 64), 256, 0, stream>>>(x, sel, tok);
  up_kernel<<<dim3(8, 16, 8), 256, 0, stream>>>(tok, W1, up_part);
  gelu_reduce_kernel<<<128, 256, 0, stream>>>(up_part, b1, b2, mid, ebar);
  down_kernel<<<dim3(32, 2, 8), 256, 0, stream>>>(mid, W2, down_part);
  ebar_reduce_kernel<<<64, 256, 0, stream>>>(down_part, ebar);
  combine_kernel<<<16384, 256, 0, stream>>>(G, ebar, y);
}